// Round 7
// baseline (478.902 us; speedup 1.0000x reference)
//
#include <hip/hip_runtime.h>

#define IN_DIM 256
#define HID    128
#define LAT    64
#define SLOTS  64   // padded CSR slots per node (Poisson(16); P(deg>64) ~ 0)
#define NBKT   16   // dst-range buckets; bucket b -> XCD b&7, phase b>>3 (2 phases)
#define FILL_BLOCKS 1024

typedef __attribute__((ext_vector_type(8))) short short8;
typedef __attribute__((ext_vector_type(4))) float floatx4;
typedef __attribute__((ext_vector_type(4))) int  intx4;
typedef __attribute__((ext_vector_type(2))) int  intx2;

// bf16 helpers (bit-level, round-to-nearest-even)
static __device__ __forceinline__ ushort f2bf(float f) {
    union { float f; uint u; } v; v.f = f;
    uint u = v.u;
    uint r = (u + 0x7fffu + ((u >> 16) & 1u)) >> 16;
    return (ushort)r;
}
static __device__ __forceinline__ float bf_lo(uint v) { return __uint_as_float(v << 16); }
static __device__ __forceinline__ float bf_hi(uint v) { return __uint_as_float(v & 0xffff0000u); }

// ---------------------------------------------------------------- phase A: scatter edges to 16 dst-range buckets
__global__ __launch_bounds__(256) void scatter_kernel(const int* __restrict__ src,
                                                      const int* __restrict__ dst,
                                                      int* __restrict__ bkt,   // int2 payload as 2x int
                                                      int* __restrict__ bkt_cnt,
                                                      int cap, int N, int E) {
    __shared__ int cntL[NBKT], baseL[NBKT], posL[NBKT];
    const int t = threadIdx.x;
    if (t < NBKT) { cntL[t] = 0; posL[t] = 0; }
    __syncthreads();
    const float sc = (float)NBKT / (float)N;
    const int e0 = blockIdx.x * 2048 + t * 8;
    int s[8], d[8];
    if (e0 + 7 < E) {
        *(int4*)(s)     = *(const int4*)(src + e0);
        *(int4*)(s + 4) = *(const int4*)(src + e0 + 4);
        *(int4*)(d)     = *(const int4*)(dst + e0);
        *(int4*)(d + 4) = *(const int4*)(dst + e0 + 4);
    } else {
        #pragma unroll
        for (int k = 0; k < 8; ++k) {
            int e = e0 + k;
            s[k] = (e < E) ? src[e] : 0;
            d[k] = (e < E) ? dst[e] : -1;
        }
    }
    int r[8];
    #pragma unroll
    for (int k = 0; k < 8; ++k) {
        r[k] = (d[k] >= 0) ? min((int)((float)d[k] * sc), NBKT - 1) : -1;
        if (r[k] >= 0) atomicAdd(&cntL[r[k]], 1);
    }
    __syncthreads();
    if (t < NBKT) baseL[t] = atomicAdd(&bkt_cnt[t], cntL[t]);
    __syncthreads();
    #pragma unroll
    for (int k = 0; k < 8; ++k) {
        if (r[k] >= 0) {
            int off = atomicAdd(&posL[r[k]], 1);
            int p = baseL[r[k]] + off;
            if (p < cap) {
                intx2 pk; pk.x = s[k]; pk.y = d[k];
                __builtin_nontemporal_store(pk,
                    (intx2*)(bkt + ((size_t)r[k] * cap + p) * 2));
            }
        }
    }
}

// ---------------------------------------------------------------- fused fill + GEMM1
// fill (blocks 0..1023) is latency-bound (0.5% VALU, 25% occ, 12% HBM);
// gemm1 (remaining blocks) is compute-bound. Role-split co-schedules them on
// complementary resources: gemm1's ~40us hides inside fill's ~75us shadow.
__global__ __launch_bounds__(256) void fill_gemm1_kernel(
        const int* __restrict__ bkt, const int* __restrict__ bkt_cnt,
        int* __restrict__ cur, int* __restrict__ csr, int cap,
        const float* __restrict__ X, const ushort* __restrict__ W1T,
        ushort* __restrict__ O, int N) {
    __shared__ ushort As[64 * 32];
    __shared__ ushort Bs[128 * 32];
    __shared__ ushort Cs[64 * 128];

    if (blockIdx.x < FILL_BLOCKS) {
        // ---- fill role: phased count-up CSR fill (unchanged from r6)
        const int xcd  = blockIdx.x & 7;
        const int slot = blockIdx.x >> 3;
        const int bpx  = FILL_BLOCKS >> 3;        // blocks per xcd
        for (int ph = 0; ph < NBKT / 8; ++ph) {
            const int r  = ph * 8 + xcd;
            const int sz = min(bkt_cnt[r], cap);
            const int* b = bkt + (size_t)r * cap * 2;
            for (int i = (slot * 256 + threadIdx.x) * 4; i + 3 < sz; i += bpx * 1024) {
                intx4 e01 = __builtin_nontemporal_load((const intx4*)(b + (size_t)i * 2));
                intx4 e23 = __builtin_nontemporal_load((const intx4*)(b + (size_t)i * 2 + 4));
                int p0 = atomicAdd(&cur[e01.y], 1);
                int p1 = atomicAdd(&cur[e01.w], 1);
                int p2 = atomicAdd(&cur[e23.y], 1);
                int p3 = atomicAdd(&cur[e23.w], 1);
                if (p0 < SLOTS) csr[(e01.y << 6) + p0] = e01.x;
                if (p1 < SLOTS) csr[(e01.w << 6) + p1] = e01.z;
                if (p2 < SLOTS) csr[(e23.y << 6) + p2] = e23.x;
                if (p3 < SLOTS) csr[(e23.w << 6) + p3] = e23.z;
            }
            if (slot == 0) {                      // tail: 0..3 entries
                int k = (sz & ~3) + threadIdx.x;
                if (k < sz) {
                    int es = b[(size_t)k * 2];
                    int ed = b[(size_t)k * 2 + 1];
                    int p = atomicAdd(&cur[ed], 1);
                    if (p < SLOTS) csr[(ed << 6) + p] = es;
                }
            }
        }
        return;
    }

    // ---- gemm1 role: t1[N,128]bf16 = x[N,256] @ W1
    const int bid  = blockIdx.x - FILL_BLOCKS;
    const int tid  = threadIdx.x;
    const int wave = tid >> 6, lane = tid & 63;
    const int q = lane >> 4, ln = lane & 15;
    const int row0 = bid * 64;
    floatx4 acc[8] = {};

    for (int k0 = 0; k0 < IN_DIM; k0 += 32) {
        #pragma unroll
        for (int t = 0; t < 2; ++t) {
            int j = t * 256 + tid;               // float4 id, 512 total
            int r = j >> 3, kc = (j & 7) * 4;
            float4 v = make_float4(0.f, 0.f, 0.f, 0.f);
            if (row0 + r < N)
                v = *(const float4*)(X + (size_t)(row0 + r) * IN_DIM + k0 + kc);
            *(ushort4*)(As + r * 32 + kc) =
                make_ushort4(f2bf(v.x), f2bf(v.y), f2bf(v.z), f2bf(v.w));
        }
        #pragma unroll
        for (int t = 0; t < 2; ++t) {
            int c = t * 256 + tid;               // 8-bf16 chunk id, 512 total
            int n = c >> 2, kc = (c & 3) * 8;
            *(int4*)(Bs + n * 32 + kc) = *(const int4*)(W1T + (size_t)n * IN_DIM + k0 + kc);
        }
        __syncthreads();
        short8 a = *(const short8*)(As + (wave * 16 + ln) * 32 + q * 8);
        #pragma unroll
        for (int t = 0; t < 8; ++t) {
            short8 b = *(const short8*)(Bs + (t * 16 + ln) * 32 + q * 8);
            acc[t] = __builtin_amdgcn_mfma_f32_16x16x32_bf16(a, b, acc[t], 0, 0, 0);
        }
        __syncthreads();
    }
    #pragma unroll
    for (int t = 0; t < 8; ++t)
        #pragma unroll
        for (int r = 0; r < 4; ++r)
            Cs[(wave * 16 + q * 4 + r) * 128 + t * 16 + ln] = f2bf(acc[t][r]);
    __syncthreads();
    #pragma unroll
    for (int t = 0; t < 4; ++t) {
        int j = t * 256 + tid;                   // int4(8 bf16) id, 1024 total
        int r = j >> 4, c8 = (j & 15) * 8;
        if (row0 + r < N)
            *(int4*)(O + (size_t)(row0 + r) * HID + c8) = *(const int4*)(Cs + r * 128 + c8);
    }
}

// ---------------------------------------------------------------- dinv: rsqrt(deg+1) (self-loop implicit in agg)
__global__ __launch_bounds__(256) void dinv_kernel(const int* __restrict__ cur,
                                                   float* __restrict__ dinv, int N) {
    int i = blockIdx.x * 256 + threadIdx.x;
    if (i < N) dinv[i] = rsqrtf((float)(cur[i] + 1));
}

// ---------------------------------------------------------------- weights -> bf16 transposed
__global__ void prep_weights(const float* __restrict__ W1, const float* __restrict__ Wmu,
                             const float* __restrict__ Wls,
                             ushort* __restrict__ W1T, ushort* __restrict__ W2T) {
    int idx = blockIdx.x * 256 + threadIdx.x;
    if (idx < IN_DIM * HID) {                       // W1: idx = k*128+n
        int n = idx & 127, k = idx >> 7;
        W1T[n * IN_DIM + k] = f2bf(W1[idx]);
    } else {
        int j = idx - IN_DIM * HID;
        if (j < HID * LAT) {                        // Wmu: j = k*64+n
            int n = j & 63, k = j >> 6;
            W2T[n * HID + k] = f2bf(Wmu[j]);
        } else {
            int jj = j - HID * LAT;
            int n = jj & 63, k = jj >> 6;
            W2T[(64 + n) * HID + k] = f2bf(Wls[jj]);
        }
    }
}

// ---------------------------------------------------------------- aggregation v7: column-half split + 8-lane edge groups
// wave handles (node, col-half). half h steered by blockIdx&7: halves segregate
// by XCD group -> each XCD reads only a 12.8MB half-table (fetch ~196->~150MB).
// 8 groups of 8 lanes: 16 edges in flight per wave (2x v6's ILP).
__global__ __launch_bounds__(256) void agg_kernel(const ushort* __restrict__ in,
                                                  ushort* __restrict__ out,
                                                  const int* __restrict__ cnt,
                                                  const int* __restrict__ csr,
                                                  const float* __restrict__ dinv,
                                                  const float* __restrict__ bias,
                                                  int N, int mode) {
    const int h   = (blockIdx.x >> 2) & 1;                      // col-half
    const int nb  = (blockIdx.x >> 3) * 4 + (blockIdx.x & 3);   // node-block
    const int wid = nb * 4 + (threadIdx.x >> 6);
    const int lane = threadIdx.x & 63;
    if (wid >= N) return;
    const int cn   = min(cnt[wid], SLOTS);        // edge count (self-loop NOT included)
    const float dd = dinv[wid];
    // ---- preload: entry + norm per lane (lanes >= cn duplicate a valid slot)
    int e    = (cn > 0) ? csr[(wid << 6) + min(lane, cn - 1)] : wid;
    float nr = dinv[e] * dd;
    const int q    = lane >> 3;                   // 8 groups of 8 lanes
    const int boff = h * 64 + (lane & 7) * 8;     // ushort col offset (16 B per lane)
    const ushort* inb = in + boff;
    float a0=0.f,a1=0.f,a2=0.f,a3=0.f,a4=0.f,a5=0.f,a6=0.f,a7=0.f;
    const int nfull = cn >> 3;                    // full groups of 8 edges
    int jj = 0;
    for (; jj + 2 <= nfull; jj += 2) {            // 16 edges per iteration
        int j0 = (jj << 3) + q, j1 = j0 + 8;
        int   s0 = __shfl(e,  j0);
        int   s1 = __shfl(e,  j1);
        float n0 = __shfl(nr, j0);
        float n1 = __shfl(nr, j1);
        uint4 v0 = *(const uint4*)(inb + (size_t)s0 * HID);
        uint4 v1 = *(const uint4*)(inb + (size_t)s1 * HID);
        a0 += bf_lo(v0.x) * n0; a1 += bf_hi(v0.x) * n0;
        a2 += bf_lo(v0.y) * n0; a3 += bf_hi(v0.y) * n0;
        a4 += bf_lo(v0.z) * n0; a5 += bf_hi(v0.z) * n0;
        a6 += bf_lo(v0.w) * n0; a7 += bf_hi(v0.w) * n0;
        a0 += bf_lo(v1.x) * n1; a1 += bf_hi(v1.x) * n1;
        a2 += bf_lo(v1.y) * n1; a3 += bf_hi(v1.y) * n1;
        a4 += bf_lo(v1.z) * n1; a5 += bf_hi(v1.z) * n1;
        a6 += bf_lo(v1.w) * n1; a7 += bf_hi(v1.w) * n1;
    }
    if (jj < nfull) {                             // leftover full group of 8
        int j0 = (jj << 3) + q;
        int   s0 = __shfl(e,  j0);
        float n0 = __shfl(nr, j0);
        uint4 v0 = *(const uint4*)(inb + (size_t)s0 * HID);
        a0 += bf_lo(v0.x) * n0; a1 += bf_hi(v0.x) * n0;
        a2 += bf_lo(v0.y) * n0; a3 += bf_hi(v0.y) * n0;
        a4 += bf_lo(v0.z) * n0; a5 += bf_hi(v0.z) * n0;
        a6 += bf_lo(v0.w) * n0; a7 += bf_hi(v0.w) * n0;
    }
    {                                             // tail: 0..7 edges
        int rem = cn - (nfull << 3);
        int jT  = max(min((nfull << 3) + q, cn - 1), 0);
        int   sT = __shfl(e,  jT);                // full-wave shfl, then predicate
        float nT = __shfl(nr, jT);
        if (q < rem) {
            uint4 v0 = *(const uint4*)(inb + (size_t)sT * HID);
            a0 += bf_lo(v0.x) * nT; a1 += bf_hi(v0.x) * nT;
            a2 += bf_lo(v0.y) * nT; a3 += bf_hi(v0.y) * nT;
            a4 += bf_lo(v0.z) * nT; a5 += bf_hi(v0.z) * nT;
            a6 += bf_lo(v0.w) * nT; a7 += bf_hi(v0.w) * nT;
        }
    }
    a0 += __shfl_xor(a0,  8); a1 += __shfl_xor(a1,  8);
    a2 += __shfl_xor(a2,  8); a3 += __shfl_xor(a3,  8);
    a4 += __shfl_xor(a4,  8); a5 += __shfl_xor(a5,  8);
    a6 += __shfl_xor(a6,  8); a7 += __shfl_xor(a7,  8);
    a0 += __shfl_xor(a0, 16); a1 += __shfl_xor(a1, 16);
    a2 += __shfl_xor(a2, 16); a3 += __shfl_xor(a3, 16);
    a4 += __shfl_xor(a4, 16); a5 += __shfl_xor(a5, 16);
    a6 += __shfl_xor(a6, 16); a7 += __shfl_xor(a7, 16);
    a0 += __shfl_xor(a0, 32); a1 += __shfl_xor(a1, 32);
    a2 += __shfl_xor(a2, 32); a3 += __shfl_xor(a3, 32);
    a4 += __shfl_xor(a4, 32); a5 += __shfl_xor(a5, 32);
    a6 += __shfl_xor(a6, 32); a7 += __shfl_xor(a7, 32);
    if (q == 0) {
        {   // implicit self-loop: dinv[wid]^2 * in[wid] (this half only)
            uint4 sv = *(const uint4*)(in + (size_t)wid * HID + boff);
            float ss = dd * dd;
            a0 += bf_lo(sv.x) * ss; a1 += bf_hi(sv.x) * ss;
            a2 += bf_lo(sv.y) * ss; a3 += bf_hi(sv.y) * ss;
            a4 += bf_lo(sv.z) * ss; a5 += bf_hi(sv.z) * ss;
            a6 += bf_lo(sv.w) * ss; a7 += bf_hi(sv.w) * ss;
        }
        if (mode) {
            float4 b0 = *(const float4*)(bias + boff);
            float4 b1 = *(const float4*)(bias + boff + 4);
            a0 = fmaxf(a0 + b0.x, 0.f); a1 = fmaxf(a1 + b0.y, 0.f);
            a2 = fmaxf(a2 + b0.z, 0.f); a3 = fmaxf(a3 + b0.w, 0.f);
            a4 = fmaxf(a4 + b1.x, 0.f); a5 = fmaxf(a5 + b1.y, 0.f);
            a6 = fmaxf(a6 + b1.z, 0.f); a7 = fmaxf(a7 + b1.w, 0.f);
        }
        uint4 pk;
        pk.x = (uint)f2bf(a0) | ((uint)f2bf(a1) << 16);
        pk.y = (uint)f2bf(a2) | ((uint)f2bf(a3) << 16);
        pk.z = (uint)f2bf(a4) | ((uint)f2bf(a5) << 16);
        pk.w = (uint)f2bf(a6) | ((uint)f2bf(a7) << 16);
        *(uint4*)(out + (size_t)wid * HID + boff) = pk;
    }
}

// ---------------------------------------------------------------- GEMM2 (MFMA bf16): mu/ls[N,64] = g[N,128] @ W2T + bias
__global__ __launch_bounds__(256) void gemm2_mfma(const ushort* __restrict__ G,
                                                  const ushort* __restrict__ W2T,
                                                  const float* __restrict__ bmu,
                                                  const float* __restrict__ bls,
                                                  float* __restrict__ mu,
                                                  float* __restrict__ ls, int N) {
    __shared__ ushort As[64 * 32];
    __shared__ ushort Bs[128 * 32];
    __shared__ float  Cs[64 * 128];
    const int tid  = threadIdx.x;
    const int wave = tid >> 6, lane = tid & 63;
    const int q = lane >> 4, ln = lane & 15;
    const int row0 = blockIdx.x * 64;
    floatx4 acc[8] = {};

    for (int k0 = 0; k0 < HID; k0 += 32) {
        {   // A: 64 rows x 32 k bf16, 256 int4 chunks, 1/thread
            int r = tid >> 2, kc = (tid & 3) * 8;
            int4 v = make_int4(0, 0, 0, 0);
            if (row0 + r < N) v = *(const int4*)(G + (size_t)(row0 + r) * HID + k0 + kc);
            *(int4*)(As + r * 32 + kc) = v;
        }
        #pragma unroll
        for (int t = 0; t < 2; ++t) {            // B: 128 n x 32 k
            int c = t * 256 + tid;
            int n = c >> 2, kc = (c & 3) * 8;
            *(int4*)(Bs + n * 32 + kc) = *(const int4*)(W2T + (size_t)n * HID + k0 + kc);
        }
        __syncthreads();
        short8 a = *(const short8*)(As + (wave * 16 + ln) * 32 + q * 8);
        #pragma unroll
        for (int t = 0; t < 8; ++t) {
            short8 b = *(const short8*)(Bs + (t * 16 + ln) * 32 + q * 8);
            acc[t] = __builtin_amdgcn_mfma_f32_16x16x32_bf16(a, b, acc[t], 0, 0, 0);
        }
        __syncthreads();
    }
    #pragma unroll
    for (int t = 0; t < 8; ++t)
        #pragma unroll
        for (int r = 0; r < 4; ++r)
            Cs[(wave * 16 + q * 4 + r) * 128 + t * 16 + ln] = acc[t][r];
    __syncthreads();
    #pragma unroll
    for (int t = 0; t < 8; ++t) {
        int j = t * 256 + tid;                   // float4 id, 2048 total
        int r = j >> 5, c4 = (j & 31) * 4;
        if (row0 + r < N) {
            float4 v = *(const float4*)(Cs + r * 128 + c4);
            if (c4 < 64) {
                float4 b = *(const float4*)(bmu + c4);
                *(float4*)(mu + (size_t)(row0 + r) * LAT + c4) =
                    make_float4(v.x + b.x, v.y + b.y, v.z + b.z, v.w + b.w);
            } else {
                float4 b = *(const float4*)(bls + (c4 - 64));
                *(float4*)(ls + (size_t)(row0 + r) * LAT + (c4 - 64)) =
                    make_float4(v.x + b.x, v.y + b.y, v.z + b.z, v.w + b.w);
            }
        }
    }
}

// ---------------------------------------------------------------- launch
extern "C" void kernel_launch(void* const* d_in, const int* in_sizes, int n_in,
                              void* d_out, int out_size, void* d_ws, size_t ws_size,
                              hipStream_t stream) {
    const float* x    = (const float*)d_in[0];
    const int*   edge = (const int*)d_in[1];
    const float* W1   = (const float*)d_in[2];
    const float* b1   = (const float*)d_in[3];
    const float* Wmu  = (const float*)d_in[4];
    const float* bmu  = (const float*)d_in[5];
    const float* Wls  = (const float*)d_in[6];
    const float* bls  = (const float*)d_in[7];

    const int N = in_sizes[0] / IN_DIM;
    const int E = in_sizes[1] / 2;
    const int cap = E / NBKT + 8192;             // bucket sigma ~300; huge slack

    const int* src = edge;
    const int* dst = edge + E;

    // workspace layout (gb reuses t1b: consumed by agg1 before agg2 writes it)
    ushort* t1b  = (ushort*)d_ws;                       // [N,128] bf16  (also gb)
    ushort* hb   = t1b + (size_t)N * HID;               // [N,128] bf16
    int*    csr  = (int*)(hb + (size_t)N * HID);        // [N,64] padded src-only CSR
    int*    bkt  = (int*)(csr + (size_t)N * SLOTS);     // [16,cap] int2 payload as 2x int
    float*  dinv = (float*)(bkt + (size_t)NBKT * cap * 2); // [N]
    int*    cur  = (int*)(dinv + N);                    // [N] slot cursor == in-degree after fill
    int* bkt_cnt = cur + N;                             // [16]
    ushort* W1T  = (ushort*)(bkt_cnt + NBKT);           // [128,256] bf16
    ushort* W2T  = W1T + IN_DIM * HID;                  // [128,128] bf16
    ushort* gb   = t1b;

    float* mu = (float*)d_out;                          // [N,64]
    float* ls = mu + (size_t)N * LAT;                   // [N,64]

    (void)hipMemsetAsync(cur, 0, (size_t)(N + NBKT) * sizeof(int), stream);  // cur + bkt_cnt

    scatter_kernel<<<(E + 2047) / 2048, 256, 0, stream>>>(src, dst, bkt, bkt_cnt, cap, N, E);
    prep_weights<<<(IN_DIM * HID + 2 * HID * LAT) / 256, 256, 0, stream>>>(W1, Wmu, Wls, W1T, W2T);

    {   // fused fill + gemm1 (independent; co-scheduled via block-role split)
        int g1Blocks = (N + 63) / 64;
        fill_gemm1_kernel<<<FILL_BLOCKS + g1Blocks, 256, 0, stream>>>(
            bkt, bkt_cnt, cur, csr, cap, x, W1T, t1b, N);
    }
    dinv_kernel<<<(N + 255) / 256, 256, 0, stream>>>(cur, dinv, N);

    {   // layer-1 aggregation + bias + relu: t1b -> hb
        int blocks = ((N + 15) / 16) * 8;        // (node-chunk, col-half) pairs
        agg_kernel<<<blocks, 256, 0, stream>>>(t1b, hb, cur, csr, dinv, b1, N, 1);
    }
    {   // layer-2 aggregation: hb -> gb (= t1b, already consumed)
        int blocks = ((N + 15) / 16) * 8;
        agg_kernel<<<blocks, 256, 0, stream>>>(hb, gb, cur, csr, dinv, nullptr, N, 0);
    }

    gemm2_mfma<<<(N + 63) / 64, 256, 0, stream>>>(gb, W2T, bmu, bls, mu, ls, N);
}

// Round 8
// 412.059 us; speedup vs baseline: 1.1622x; 1.1622x over previous
//
#include <hip/hip_runtime.h>

#define IN_DIM 256
#define HID    128
#define LAT    64
#define SLOTS  64    // padded CSR slots per node (Poisson(16); P(deg>64) ~ 0)
#define RANGE  200   // nodes per bucket (compile-time: LDS sizing + fast div)
#define MAXBKT 512   // >= ceil(N/RANGE) = 500

typedef __attribute__((ext_vector_type(8))) short short8;
typedef __attribute__((ext_vector_type(4))) float floatx4;
typedef __attribute__((ext_vector_type(4))) int  intx4;
typedef __attribute__((ext_vector_type(2))) int  intx2;

// bf16 helpers (bit-level, round-to-nearest-even)
static __device__ __forceinline__ ushort f2bf(float f) {
    union { float f; uint u; } v; v.f = f;
    uint u = v.u;
    uint r = (u + 0x7fffu + ((u >> 16) & 1u)) >> 16;
    return (ushort)r;
}
static __device__ __forceinline__ float bf_lo(uint v) { return __uint_as_float(v << 16); }
static __device__ __forceinline__ float bf_hi(uint v) { return __uint_as_float(v & 0xffff0000u); }

// ---------------------------------------------------------------- phase A: scatter edges to 500 fine dst-range buckets
// Single visit of (src,dst). Per-block LDS counts -> bulk cursor claim per
// bucket. Bucket r covers nodes [r*RANGE, (r+1)*RANGE). d/RANGE is a
// compile-time magic-multiply. NT stores keep the write-once stream out of L2.
__global__ __launch_bounds__(256) void scatter_kernel(const int* __restrict__ src,
                                                      const int* __restrict__ dst,
                                                      int* __restrict__ bkt,   // int2 payload as 2x int
                                                      int* __restrict__ bkt_cnt,
                                                      int cap, int nbkt, int E) {
    __shared__ int cntL[MAXBKT], baseL[MAXBKT], posL[MAXBKT];
    const int t = threadIdx.x;
    for (int b = t; b < nbkt; b += 256) { cntL[b] = 0; posL[b] = 0; }
    __syncthreads();
    const int e0 = blockIdx.x * 2048 + t * 8;
    int s[8], d[8];
    if (e0 + 7 < E) {
        *(int4*)(s)     = *(const int4*)(src + e0);
        *(int4*)(s + 4) = *(const int4*)(src + e0 + 4);
        *(int4*)(d)     = *(const int4*)(dst + e0);
        *(int4*)(d + 4) = *(const int4*)(dst + e0 + 4);
    } else {
        #pragma unroll
        for (int k = 0; k < 8; ++k) {
            int e = e0 + k;
            s[k] = (e < E) ? src[e] : 0;
            d[k] = (e < E) ? dst[e] : -1;
        }
    }
    int r[8];
    #pragma unroll
    for (int k = 0; k < 8; ++k) {
        r[k] = (d[k] >= 0) ? (d[k] / RANGE) : -1;
        if (r[k] >= 0) atomicAdd(&cntL[r[k]], 1);
    }
    __syncthreads();
    for (int b = t; b < nbkt; b += 256) {
        int c = cntL[b];
        baseL[b] = c ? atomicAdd(&bkt_cnt[b], c) : 0;
    }
    __syncthreads();
    #pragma unroll
    for (int k = 0; k < 8; ++k) {
        if (r[k] >= 0) {
            int off = atomicAdd(&posL[r[k]], 1);
            int p = baseL[r[k]] + off;
            if (p < cap) {
                intx2 pk; pk.x = s[k]; pk.y = d[k];
                __builtin_nontemporal_store(pk,
                    (intx2*)(bkt + ((size_t)r[k] * cap + p) * 2));
            }
        }
    }
}

// ---------------------------------------------------------------- phase B: LDS-binned CSR fill (no global atomics)
// One block per bucket (200 nodes, ~3200 edges). Edges are binned into LDS
// per-node slot arrays via LDS atomics; then the whole 51KB region streams
// out as dense coalesced int4 stores (csr written exactly once, amp 1.0).
// cur (true in-degree) also written densely -> no cur memset needed.
__global__ __launch_bounds__(256) void fill_bin_kernel(const int* __restrict__ bkt,
                                                       const int* __restrict__ bkt_cnt,
                                                       int* __restrict__ cur,
                                                       int* __restrict__ csr,
                                                       int cap, int N) {
    __shared__ int lcnt[RANGE];
    __shared__ int lslots[RANGE * SLOTS];        // 200*64*4B = 51200 B
    const int r  = blockIdx.x;
    const int lo = r * RANGE;
    const int R  = min(RANGE, N - lo);
    if (R <= 0) return;
    for (int j = threadIdx.x; j < R; j += 256) lcnt[j] = 0;
    __syncthreads();
    const int sz = min(bkt_cnt[r], cap);
    const int* b = bkt + (size_t)r * cap * 2;
    for (int i = threadIdx.x; i < sz; i += 256) {
        intx2 e = __builtin_nontemporal_load((const intx2*)(b + (size_t)i * 2));
        int ln = e.y - lo;
        int p = atomicAdd(&lcnt[ln], 1);
        if (p < SLOTS) lslots[(ln << 6) + p] = e.x;
    }
    __syncthreads();
    const int nInt4 = R << 4;                    // R*64/4 int4 chunks
    int4* dstp = (int4*)(csr + ((size_t)lo << 6));
    const int4* srcp = (const int4*)lslots;
    for (int j = threadIdx.x; j < nInt4; j += 256)
        dstp[j] = srcp[j];                       // slots >= lcnt are garbage; agg never reads them
    for (int j = threadIdx.x; j < R; j += 256)
        cur[lo + j] = lcnt[j];                   // true in-degree (even if clamped at SLOTS)
}

// ---------------------------------------------------------------- dinv: rsqrt(deg+1) (self-loop implicit in agg)
__global__ __launch_bounds__(256) void dinv_kernel(const int* __restrict__ cur,
                                                   float* __restrict__ dinv, int N) {
    int i = blockIdx.x * 256 + threadIdx.x;
    if (i < N) dinv[i] = rsqrtf((float)(cur[i] + 1));
}

// ---------------------------------------------------------------- weights -> bf16 transposed
__global__ void prep_weights(const float* __restrict__ W1, const float* __restrict__ Wmu,
                             const float* __restrict__ Wls,
                             ushort* __restrict__ W1T, ushort* __restrict__ W2T) {
    int idx = blockIdx.x * 256 + threadIdx.x;
    if (idx < IN_DIM * HID) {                       // W1: idx = k*128+n
        int n = idx & 127, k = idx >> 7;
        W1T[n * IN_DIM + k] = f2bf(W1[idx]);
    } else {
        int j = idx - IN_DIM * HID;
        if (j < HID * LAT) {                        // Wmu: j = k*64+n
            int n = j & 63, k = j >> 6;
            W2T[n * HID + k] = f2bf(Wmu[j]);
        } else {
            int jj = j - HID * LAT;
            int n = jj & 63, k = jj >> 6;
            W2T[(64 + n) * HID + k] = f2bf(Wls[jj]);
        }
    }
}

// ---------------------------------------------------------------- GEMM1 (MFMA bf16): t1[N,128]bf16 = x[N,256] @ W1
__global__ __launch_bounds__(256) void gemm1_mfma(const float* __restrict__ X,
                                                  const ushort* __restrict__ W1T,
                                                  ushort* __restrict__ O, int N) {
    __shared__ ushort As[64 * 32];
    __shared__ ushort Bs[128 * 32];
    __shared__ ushort Cs[64 * 128];
    const int tid  = threadIdx.x;
    const int wave = tid >> 6, lane = tid & 63;
    const int q = lane >> 4, ln = lane & 15;
    const int row0 = blockIdx.x * 64;
    floatx4 acc[8] = {};

    for (int k0 = 0; k0 < IN_DIM; k0 += 32) {
        #pragma unroll
        for (int t = 0; t < 2; ++t) {
            int j = t * 256 + tid;               // float4 id, 512 total
            int r = j >> 3, kc = (j & 7) * 4;
            float4 v = make_float4(0.f, 0.f, 0.f, 0.f);
            if (row0 + r < N)
                v = *(const float4*)(X + (size_t)(row0 + r) * IN_DIM + k0 + kc);
            *(ushort4*)(As + r * 32 + kc) =
                make_ushort4(f2bf(v.x), f2bf(v.y), f2bf(v.z), f2bf(v.w));
        }
        #pragma unroll
        for (int t = 0; t < 2; ++t) {
            int c = t * 256 + tid;               // 8-bf16 chunk id, 512 total
            int n = c >> 2, kc = (c & 3) * 8;
            *(int4*)(Bs + n * 32 + kc) = *(const int4*)(W1T + (size_t)n * IN_DIM + k0 + kc);
        }
        __syncthreads();
        short8 a = *(const short8*)(As + (wave * 16 + ln) * 32 + q * 8);
        #pragma unroll
        for (int t = 0; t < 8; ++t) {
            short8 b = *(const short8*)(Bs + (t * 16 + ln) * 32 + q * 8);
            acc[t] = __builtin_amdgcn_mfma_f32_16x16x32_bf16(a, b, acc[t], 0, 0, 0);
        }
        __syncthreads();
    }
    #pragma unroll
    for (int t = 0; t < 8; ++t)
        #pragma unroll
        for (int r = 0; r < 4; ++r)
            Cs[(wave * 16 + q * 4 + r) * 128 + t * 16 + ln] = f2bf(acc[t][r]);
    __syncthreads();
    #pragma unroll
    for (int t = 0; t < 4; ++t) {
        int j = t * 256 + tid;                   // int4(8 bf16) id, 1024 total
        int r = j >> 4, c8 = (j & 15) * 8;
        if (row0 + r < N)
            *(int4*)(O + (size_t)(row0 + r) * HID + c8) = *(const int4*)(Cs + r * 128 + c8);
    }
}

// ---------------------------------------------------------------- aggregation (round-6 v6): register-preloaded indices + implicit self-loop
__global__ __launch_bounds__(256) void agg_kernel(const ushort* __restrict__ in,
                                                  ushort* __restrict__ out,
                                                  const int* __restrict__ cnt,
                                                  const int* __restrict__ csr,
                                                  const float* __restrict__ dinv,
                                                  const float* __restrict__ bias,
                                                  int N, int mode) {
    int wid  = (blockIdx.x * 256 + threadIdx.x) >> 6;
    int lane = threadIdx.x & 63;
    if (wid >= N) return;
    const int cn   = min(cnt[wid], SLOTS);        // edge count (self-loop NOT included)
    const float dd = dinv[wid];
    // ---- preload: entry + norm per lane (lanes >= cn duplicate a valid slot)
    int e    = (cn > 0) ? csr[(wid << 6) + min(lane, cn - 1)] : wid;
    float nr = dinv[e] * dd;
    const int q    = lane >> 4;
    const int boff = (lane & 15) * 8;             // ushort col offset (16 B per lane)
    const ushort* inb = in + boff;
    float a0=0.f,a1=0.f,a2=0.f,a3=0.f,a4=0.f,a5=0.f,a6=0.f,a7=0.f;
    const int nfull = cn >> 2;                    // full groups of 4 edges
    int jj = 0;
    for (; jj + 2 <= nfull; jj += 2) {            // 8 edges per iteration
        int j0 = (jj << 2) + q, j1 = j0 + 4;
        int   s0 = __shfl(e,  j0);
        int   s1 = __shfl(e,  j1);
        float n0 = __shfl(nr, j0);
        float n1 = __shfl(nr, j1);
        uint4 v0 = *(const uint4*)(inb + (size_t)s0 * HID);
        uint4 v1 = *(const uint4*)(inb + (size_t)s1 * HID);
        a0 += bf_lo(v0.x) * n0; a1 += bf_hi(v0.x) * n0;
        a2 += bf_lo(v0.y) * n0; a3 += bf_hi(v0.y) * n0;
        a4 += bf_lo(v0.z) * n0; a5 += bf_hi(v0.z) * n0;
        a6 += bf_lo(v0.w) * n0; a7 += bf_hi(v0.w) * n0;
        a0 += bf_lo(v1.x) * n1; a1 += bf_hi(v1.x) * n1;
        a2 += bf_lo(v1.y) * n1; a3 += bf_hi(v1.y) * n1;
        a4 += bf_lo(v1.z) * n1; a5 += bf_hi(v1.z) * n1;
        a6 += bf_lo(v1.w) * n1; a7 += bf_hi(v1.w) * n1;
    }
    if (jj < nfull) {                             // leftover full group of 4
        int j0 = (jj << 2) + q;
        int   s0 = __shfl(e,  j0);
        float n0 = __shfl(nr, j0);
        uint4 v0 = *(const uint4*)(inb + (size_t)s0 * HID);
        a0 += bf_lo(v0.x) * n0; a1 += bf_hi(v0.x) * n0;
        a2 += bf_lo(v0.y) * n0; a3 += bf_hi(v0.y) * n0;
        a4 += bf_lo(v0.z) * n0; a5 += bf_hi(v0.z) * n0;
        a6 += bf_lo(v0.w) * n0; a7 += bf_hi(v0.w) * n0;
    }
    {                                             // tail: 0..3 edges
        int rem = cn - (nfull << 2);
        int jT  = max(min((nfull << 2) + q, cn - 1), 0);
        int   sT = __shfl(e,  jT);                // full-wave shfl, then predicate
        float nT = __shfl(nr, jT);
        if (q < rem) {
            uint4 v0 = *(const uint4*)(inb + (size_t)sT * HID);
            a0 += bf_lo(v0.x) * nT; a1 += bf_hi(v0.x) * nT;
            a2 += bf_lo(v0.y) * nT; a3 += bf_hi(v0.y) * nT;
            a4 += bf_lo(v0.z) * nT; a5 += bf_hi(v0.z) * nT;
            a6 += bf_lo(v0.w) * nT; a7 += bf_hi(v0.w) * nT;
        }
    }
    a0 += __shfl_xor(a0, 16); a1 += __shfl_xor(a1, 16);
    a2 += __shfl_xor(a2, 16); a3 += __shfl_xor(a3, 16);
    a4 += __shfl_xor(a4, 16); a5 += __shfl_xor(a5, 16);
    a6 += __shfl_xor(a6, 16); a7 += __shfl_xor(a7, 16);
    a0 += __shfl_xor(a0, 32); a1 += __shfl_xor(a1, 32);
    a2 += __shfl_xor(a2, 32); a3 += __shfl_xor(a3, 32);
    a4 += __shfl_xor(a4, 32); a5 += __shfl_xor(a5, 32);
    a6 += __shfl_xor(a6, 32); a7 += __shfl_xor(a7, 32);
    if (q == 0) {
        {   // implicit self-loop: dinv[wid]^2 * in[wid]
            uint4 sv = *(const uint4*)(in + (size_t)wid * HID + boff);
            float ss = dd * dd;
            a0 += bf_lo(sv.x) * ss; a1 += bf_hi(sv.x) * ss;
            a2 += bf_lo(sv.y) * ss; a3 += bf_hi(sv.y) * ss;
            a4 += bf_lo(sv.z) * ss; a5 += bf_hi(sv.z) * ss;
            a6 += bf_lo(sv.w) * ss; a7 += bf_hi(sv.w) * ss;
        }
        if (mode) {
            float4 b0 = *(const float4*)(bias + boff);
            float4 b1 = *(const float4*)(bias + boff + 4);
            a0 = fmaxf(a0 + b0.x, 0.f); a1 = fmaxf(a1 + b0.y, 0.f);
            a2 = fmaxf(a2 + b0.z, 0.f); a3 = fmaxf(a3 + b0.w, 0.f);
            a4 = fmaxf(a4 + b1.x, 0.f); a5 = fmaxf(a5 + b1.y, 0.f);
            a6 = fmaxf(a6 + b1.z, 0.f); a7 = fmaxf(a7 + b1.w, 0.f);
        }
        uint4 pk;
        pk.x = (uint)f2bf(a0) | ((uint)f2bf(a1) << 16);
        pk.y = (uint)f2bf(a2) | ((uint)f2bf(a3) << 16);
        pk.z = (uint)f2bf(a4) | ((uint)f2bf(a5) << 16);
        pk.w = (uint)f2bf(a6) | ((uint)f2bf(a7) << 16);
        *(uint4*)(out + (size_t)wid * HID + boff) = pk;
    }
}

// ---------------------------------------------------------------- GEMM2 (MFMA bf16): mu/ls[N,64] = g[N,128] @ W2T + bias
__global__ __launch_bounds__(256) void gemm2_mfma(const ushort* __restrict__ G,
                                                  const ushort* __restrict__ W2T,
                                                  const float* __restrict__ bmu,
                                                  const float* __restrict__ bls,
                                                  float* __restrict__ mu,
                                                  float* __restrict__ ls, int N) {
    __shared__ ushort As[64 * 32];
    __shared__ ushort Bs[128 * 32];
    __shared__ float  Cs[64 * 128];
    const int tid  = threadIdx.x;
    const int wave = tid >> 6, lane = tid & 63;
    const int q = lane >> 4, ln = lane & 15;
    const int row0 = blockIdx.x * 64;
    floatx4 acc[8] = {};

    for (int k0 = 0; k0 < HID; k0 += 32) {
        {   // A: 64 rows x 32 k bf16, 256 int4 chunks, 1/thread
            int r = tid >> 2, kc = (tid & 3) * 8;
            int4 v = make_int4(0, 0, 0, 0);
            if (row0 + r < N) v = *(const int4*)(G + (size_t)(row0 + r) * HID + k0 + kc);
            *(int4*)(As + r * 32 + kc) = v;
        }
        #pragma unroll
        for (int t = 0; t < 2; ++t) {            // B: 128 n x 32 k
            int c = t * 256 + tid;
            int n = c >> 2, kc = (c & 3) * 8;
            *(int4*)(Bs + n * 32 + kc) = *(const int4*)(W2T + (size_t)n * HID + k0 + kc);
        }
        __syncthreads();
        short8 a = *(const short8*)(As + (wave * 16 + ln) * 32 + q * 8);
        #pragma unroll
        for (int t = 0; t < 8; ++t) {
            short8 b = *(const short8*)(Bs + (t * 16 + ln) * 32 + q * 8);
            acc[t] = __builtin_amdgcn_mfma_f32_16x16x32_bf16(a, b, acc[t], 0, 0, 0);
        }
        __syncthreads();
    }
    #pragma unroll
    for (int t = 0; t < 8; ++t)
        #pragma unroll
        for (int r = 0; r < 4; ++r)
            Cs[(wave * 16 + q * 4 + r) * 128 + t * 16 + ln] = acc[t][r];
    __syncthreads();
    #pragma unroll
    for (int t = 0; t < 8; ++t) {
        int j = t * 256 + tid;                   // float4 id, 2048 total
        int r = j >> 5, c4 = (j & 31) * 4;
        if (row0 + r < N) {
            float4 v = *(const float4*)(Cs + r * 128 + c4);
            if (c4 < 64) {
                float4 b = *(const float4*)(bmu + c4);
                *(float4*)(mu + (size_t)(row0 + r) * LAT + c4) =
                    make_float4(v.x + b.x, v.y + b.y, v.z + b.z, v.w + b.w);
            } else {
                float4 b = *(const float4*)(bls + (c4 - 64));
                *(float4*)(ls + (size_t)(row0 + r) * LAT + (c4 - 64)) =
                    make_float4(v.x + b.x, v.y + b.y, v.z + b.z, v.w + b.w);
            }
        }
    }
}

// ---------------------------------------------------------------- launch
extern "C" void kernel_launch(void* const* d_in, const int* in_sizes, int n_in,
                              void* d_out, int out_size, void* d_ws, size_t ws_size,
                              hipStream_t stream) {
    const float* x    = (const float*)d_in[0];
    const int*   edge = (const int*)d_in[1];
    const float* W1   = (const float*)d_in[2];
    const float* b1   = (const float*)d_in[3];
    const float* Wmu  = (const float*)d_in[4];
    const float* bmu  = (const float*)d_in[5];
    const float* Wls  = (const float*)d_in[6];
    const float* bls  = (const float*)d_in[7];

    const int N    = in_sizes[0] / IN_DIM;
    const int E    = in_sizes[1] / 2;
    const int nbkt = (N + RANGE - 1) / RANGE;    // 500 at N=100000
    const int cap  = 4096;                       // bucket mean 3200, sigma ~57

    const int* src = edge;
    const int* dst = edge + E;

    // workspace layout (gb reuses t1b: consumed by agg1 before agg2 writes it)
    ushort* t1b  = (ushort*)d_ws;                        // [N,128] bf16  (also gb)
    ushort* hb   = t1b + (size_t)N * HID;                // [N,128] bf16
    int*    csr  = (int*)(hb + (size_t)N * HID);         // [N,64] padded src-only CSR
    int*    bkt  = (int*)(csr + (size_t)N * SLOTS);      // [MAXBKT,cap] int2 payload as 2x int
    float*  dinv = (float*)(bkt + (size_t)MAXBKT * cap * 2); // [N]
    int*    cur  = (int*)(dinv + N);                     // [N] in-degree (written densely by fill)
    int* bkt_cnt = cur + N;                              // [MAXBKT]
    ushort* W1T  = (ushort*)(bkt_cnt + MAXBKT);          // [128,256] bf16
    ushort* W2T  = W1T + IN_DIM * HID;                   // [128,128] bf16
    ushort* gb   = t1b;

    float* mu = (float*)d_out;                           // [N,64]
    float* ls = mu + (size_t)N * LAT;                    // [N,64]

    (void)hipMemsetAsync(bkt_cnt, 0, (size_t)MAXBKT * sizeof(int), stream);

    scatter_kernel<<<(E + 2047) / 2048, 256, 0, stream>>>(src, dst, bkt, bkt_cnt, cap, nbkt, E);
    fill_bin_kernel<<<nbkt, 256, 0, stream>>>(bkt, bkt_cnt, cur, csr, cap, N);
    dinv_kernel<<<(N + 255) / 256, 256, 0, stream>>>(cur, dinv, N);

    prep_weights<<<(IN_DIM * HID + 2 * HID * LAT) / 256, 256, 0, stream>>>(W1, Wmu, Wls, W1T, W2T);
    gemm1_mfma<<<(N + 63) / 64, 256, 0, stream>>>(x, W1T, t1b, N);

    {   // layer-1 aggregation + bias + relu: t1b -> hb
        int blocks = (int)(((long long)N * 64 + 255) / 256);
        agg_kernel<<<blocks, 256, 0, stream>>>(t1b, hb, cur, csr, dinv, b1, N, 1);
    }
    {   // layer-2 aggregation: hb -> gb (= t1b, already consumed)
        int blocks = (int)(((long long)N * 64 + 255) / 256);
        agg_kernel<<<blocks, 256, 0, stream>>>(hb, gb, cur, csr, dinv, nullptr, N, 0);
    }

    gemm2_mfma<<<(N + 63) / 64, 256, 0, stream>>>(gb, W2T, bmu, bls, mu, ls, N);
}

// Round 9
// 373.978 us; speedup vs baseline: 1.2806x; 1.1018x over previous
//
#include <hip/hip_runtime.h>

#define IN_DIM 256
#define HID    128
#define LAT    64
#define SLOTS  64    // padded CSR slots per node (Poisson(16); P(deg>64) ~ 0)
#define RANGE  200   // nodes per bucket (compile-time: LDS sizing + fast div)
#define MAXBKT 512   // >= ceil(N/RANGE) = 500

typedef __attribute__((ext_vector_type(8))) short short8;
typedef __attribute__((ext_vector_type(4))) float floatx4;
typedef __attribute__((ext_vector_type(4))) int  intx4;
typedef __attribute__((ext_vector_type(2))) int  intx2;

// bf16 helpers (bit-level, round-to-nearest-even)
static __device__ __forceinline__ ushort f2bf(float f) {
    union { float f; uint u; } v; v.f = f;
    uint u = v.u;
    uint r = (u + 0x7fffu + ((u >> 16) & 1u)) >> 16;
    return (ushort)r;
}
static __device__ __forceinline__ float bf_lo(uint v) { return __uint_as_float(v << 16); }
static __device__ __forceinline__ float bf_hi(uint v) { return __uint_as_float(v & 0xffff0000u); }

// ---------------------------------------------------------------- fused scatter + GEMM1 (block-role split)
// scatter (782 short blocks, latency-bound, 22% occ) and gemm1 (compute-bound)
// are independent. All scatter blocks fit co-resident at t=0; they retire fast
// and gemm1 backfills -> overlap. (Round-7 fill fusion failed because its 1024
// blocks were LONG-running phase loops; scatter blocks are short.)
// LDS union: gemm1 needs 28KB; scatter reuses the first 6KB.
__global__ __launch_bounds__(256) void scatter_gemm1_kernel(
        const int* __restrict__ src, const int* __restrict__ dst,
        int* __restrict__ bkt, int* __restrict__ bkt_cnt,
        int cap, int nbkt, int E, int sblocks,
        const float* __restrict__ X, const ushort* __restrict__ W1T,
        ushort* __restrict__ O, int N) {
    __shared__ __align__(16) char smem[28 * 1024];

    if ((int)blockIdx.x < sblocks) {
        // ---- scatter role: bin edges to 500 dst-range buckets
        int* cntL  = (int*)smem;                  // [MAXBKT]
        int* baseL = cntL + MAXBKT;
        int* posL  = baseL + MAXBKT;
        const int t = threadIdx.x;
        for (int b = t; b < nbkt; b += 256) { cntL[b] = 0; posL[b] = 0; }
        __syncthreads();
        const int e0 = blockIdx.x * 2048 + t * 8;
        int s[8], d[8];
        if (e0 + 7 < E) {
            *(int4*)(s)     = *(const int4*)(src + e0);
            *(int4*)(s + 4) = *(const int4*)(src + e0 + 4);
            *(int4*)(d)     = *(const int4*)(dst + e0);
            *(int4*)(d + 4) = *(const int4*)(dst + e0 + 4);
        } else {
            #pragma unroll
            for (int k = 0; k < 8; ++k) {
                int e = e0 + k;
                s[k] = (e < E) ? src[e] : 0;
                d[k] = (e < E) ? dst[e] : -1;
            }
        }
        int r[8];
        #pragma unroll
        for (int k = 0; k < 8; ++k) {
            r[k] = (d[k] >= 0) ? (d[k] / RANGE) : -1;
            if (r[k] >= 0) atomicAdd(&cntL[r[k]], 1);
        }
        __syncthreads();
        for (int b = t; b < nbkt; b += 256) {
            int c = cntL[b];
            baseL[b] = c ? atomicAdd(&bkt_cnt[b], c) : 0;
        }
        __syncthreads();
        #pragma unroll
        for (int k = 0; k < 8; ++k) {
            if (r[k] >= 0) {
                int off = atomicAdd(&posL[r[k]], 1);
                int p = baseL[r[k]] + off;
                if (p < cap) {
                    // plain store (NOT non-temporal): adjacent claims from
                    // concurrent blocks merge in L2 before writeback.
                    *(intx2*)(bkt + ((size_t)r[k] * cap + p) * 2) =
                        (intx2){s[k], d[k]};
                }
            }
        }
        return;
    }

    // ---- gemm1 role: t1[N,128]bf16 = x[N,256] @ W1
    ushort* As = (ushort*)smem;                   // [64*32]
    ushort* Bs = As + 64 * 32;                    // [128*32]
    ushort* Cs = Bs + 128 * 32;                   // [64*128]
    const int bid  = blockIdx.x - sblocks;
    const int tid  = threadIdx.x;
    const int wave = tid >> 6, lane = tid & 63;
    const int q = lane >> 4, ln = lane & 15;
    const int row0 = bid * 64;
    floatx4 acc[8] = {};

    for (int k0 = 0; k0 < IN_DIM; k0 += 32) {
        #pragma unroll
        for (int t = 0; t < 2; ++t) {
            int j = t * 256 + tid;               // float4 id, 512 total
            int r = j >> 3, kc = (j & 7) * 4;
            float4 v = make_float4(0.f, 0.f, 0.f, 0.f);
            if (row0 + r < N)
                v = *(const float4*)(X + (size_t)(row0 + r) * IN_DIM + k0 + kc);
            *(ushort4*)(As + r * 32 + kc) =
                make_ushort4(f2bf(v.x), f2bf(v.y), f2bf(v.z), f2bf(v.w));
        }
        #pragma unroll
        for (int t = 0; t < 2; ++t) {
            int c = t * 256 + tid;               // 8-bf16 chunk id, 512 total
            int n = c >> 2, kc = (c & 3) * 8;
            *(int4*)(Bs + n * 32 + kc) = *(const int4*)(W1T + (size_t)n * IN_DIM + k0 + kc);
        }
        __syncthreads();
        short8 a = *(const short8*)(As + (wave * 16 + ln) * 32 + q * 8);
        #pragma unroll
        for (int t = 0; t < 8; ++t) {
            short8 b = *(const short8*)(Bs + (t * 16 + ln) * 32 + q * 8);
            acc[t] = __builtin_amdgcn_mfma_f32_16x16x32_bf16(a, b, acc[t], 0, 0, 0);
        }
        __syncthreads();
    }
    #pragma unroll
    for (int t = 0; t < 8; ++t)
        #pragma unroll
        for (int r = 0; r < 4; ++r)
            Cs[(wave * 16 + q * 4 + r) * 128 + t * 16 + ln] = f2bf(acc[t][r]);
    __syncthreads();
    #pragma unroll
    for (int t = 0; t < 4; ++t) {
        int j = t * 256 + tid;                   // int4(8 bf16) id, 1024 total
        int r = j >> 4, c8 = (j & 15) * 8;
        if (row0 + r < N)
            *(int4*)(O + (size_t)(row0 + r) * HID + c8) = *(const int4*)(Cs + r * 128 + c8);
    }
}

// ---------------------------------------------------------------- phase B: LDS-binned CSR fill (no global atomics)
// One block per bucket (200 nodes, ~3200 edges). Edges binned into LDS slot
// arrays via LDS atomics; whole 51KB region streams out dense+coalesced.
// dinv folded in (lcnt already in LDS).
__global__ __launch_bounds__(256) void fill_bin_kernel(const int* __restrict__ bkt,
                                                       const int* __restrict__ bkt_cnt,
                                                       int* __restrict__ cur,
                                                       float* __restrict__ dinv,
                                                       int* __restrict__ csr,
                                                       int cap, int N) {
    __shared__ int lcnt[RANGE];
    __shared__ int lslots[RANGE * SLOTS];        // 200*64*4B = 51200 B
    const int r  = blockIdx.x;
    const int lo = r * RANGE;
    const int R  = min(RANGE, N - lo);
    if (R <= 0) return;
    for (int j = threadIdx.x; j < R; j += 256) lcnt[j] = 0;
    __syncthreads();
    const int sz = min(bkt_cnt[r], cap);
    const int* b = bkt + (size_t)r * cap * 2;
    for (int i = threadIdx.x; i < sz; i += 256) {
        intx2 e = __builtin_nontemporal_load((const intx2*)(b + (size_t)i * 2));
        int ln = e.y - lo;
        int p = atomicAdd(&lcnt[ln], 1);
        if (p < SLOTS) lslots[(ln << 6) + p] = e.x;
    }
    __syncthreads();
    const int nInt4 = R << 4;                    // R*64/4 int4 chunks
    int4* dstp = (int4*)(csr + ((size_t)lo << 6));
    const int4* srcp = (const int4*)lslots;
    for (int j = threadIdx.x; j < nInt4; j += 256)
        dstp[j] = srcp[j];                       // slots >= lcnt are garbage; agg never reads them
    for (int j = threadIdx.x; j < R; j += 256) {
        int c = lcnt[j];
        cur[lo + j]  = c;                        // true in-degree
        dinv[lo + j] = rsqrtf((float)(c + 1));   // incl. self-loop
    }
}

// ---------------------------------------------------------------- weights -> bf16 transposed
__global__ void prep_weights(const float* __restrict__ W1, const float* __restrict__ Wmu,
                             const float* __restrict__ Wls,
                             ushort* __restrict__ W1T, ushort* __restrict__ W2T) {
    int idx = blockIdx.x * 256 + threadIdx.x;
    if (idx < IN_DIM * HID) {                       // W1: idx = k*128+n
        int n = idx & 127, k = idx >> 7;
        W1T[n * IN_DIM + k] = f2bf(W1[idx]);
    } else {
        int j = idx - IN_DIM * HID;
        if (j < HID * LAT) {                        // Wmu: j = k*64+n
            int n = j & 63, k = j >> 6;
            W2T[n * HID + k] = f2bf(Wmu[j]);
        } else {
            int jj = j - HID * LAT;
            int n = jj & 63, k = jj >> 6;
            W2T[(64 + n) * HID + k] = f2bf(Wls[jj]);
        }
    }
}

// ---------------------------------------------------------------- aggregation: register-preloaded indices + implicit self-loop
__global__ __launch_bounds__(256) void agg_kernel(const ushort* __restrict__ in,
                                                  ushort* __restrict__ out,
                                                  const int* __restrict__ cnt,
                                                  const int* __restrict__ csr,
                                                  const float* __restrict__ dinv,
                                                  const float* __restrict__ bias,
                                                  int N, int mode) {
    int wid  = (blockIdx.x * 256 + threadIdx.x) >> 6;
    int lane = threadIdx.x & 63;
    if (wid >= N) return;
    const int cn   = min(cnt[wid], SLOTS);        // edge count (self-loop NOT included)
    const float dd = dinv[wid];
    // ---- preload: entry + norm per lane (lanes >= cn duplicate a valid slot)
    int e    = (cn > 0) ? csr[(wid << 6) + min(lane, cn - 1)] : wid;
    float nr = dinv[e] * dd;
    const int q    = lane >> 4;
    const int boff = (lane & 15) * 8;             // ushort col offset (16 B per lane)
    const ushort* inb = in + boff;
    float a0=0.f,a1=0.f,a2=0.f,a3=0.f,a4=0.f,a5=0.f,a6=0.f,a7=0.f;
    const int nfull = cn >> 2;                    // full groups of 4 edges
    int jj = 0;
    for (; jj + 2 <= nfull; jj += 2) {            // 8 edges per iteration
        int j0 = (jj << 2) + q, j1 = j0 + 4;
        int   s0 = __shfl(e,  j0);
        int   s1 = __shfl(e,  j1);
        float n0 = __shfl(nr, j0);
        float n1 = __shfl(nr, j1);
        uint4 v0 = *(const uint4*)(inb + (size_t)s0 * HID);
        uint4 v1 = *(const uint4*)(inb + (size_t)s1 * HID);
        a0 += bf_lo(v0.x) * n0; a1 += bf_hi(v0.x) * n0;
        a2 += bf_lo(v0.y) * n0; a3 += bf_hi(v0.y) * n0;
        a4 += bf_lo(v0.z) * n0; a5 += bf_hi(v0.z) * n0;
        a6 += bf_lo(v0.w) * n0; a7 += bf_hi(v0.w) * n0;
        a0 += bf_lo(v1.x) * n1; a1 += bf_hi(v1.x) * n1;
        a2 += bf_lo(v1.y) * n1; a3 += bf_hi(v1.y) * n1;
        a4 += bf_lo(v1.z) * n1; a5 += bf_hi(v1.z) * n1;
        a6 += bf_lo(v1.w) * n1; a7 += bf_hi(v1.w) * n1;
    }
    if (jj < nfull) {                             // leftover full group of 4
        int j0 = (jj << 2) + q;
        int   s0 = __shfl(e,  j0);
        float n0 = __shfl(nr, j0);
        uint4 v0 = *(const uint4*)(inb + (size_t)s0 * HID);
        a0 += bf_lo(v0.x) * n0; a1 += bf_hi(v0.x) * n0;
        a2 += bf_lo(v0.y) * n0; a3 += bf_hi(v0.y) * n0;
        a4 += bf_lo(v0.z) * n0; a5 += bf_hi(v0.z) * n0;
        a6 += bf_lo(v0.w) * n0; a7 += bf_hi(v0.w) * n0;
    }
    {                                             // tail: 0..3 edges
        int rem = cn - (nfull << 2);
        int jT  = max(min((nfull << 2) + q, cn - 1), 0);
        int   sT = __shfl(e,  jT);                // full-wave shfl, then predicate
        float nT = __shfl(nr, jT);
        if (q < rem) {
            uint4 v0 = *(const uint4*)(inb + (size_t)sT * HID);
            a0 += bf_lo(v0.x) * nT; a1 += bf_hi(v0.x) * nT;
            a2 += bf_lo(v0.y) * nT; a3 += bf_hi(v0.y) * nT;
            a4 += bf_lo(v0.z) * nT; a5 += bf_hi(v0.z) * nT;
            a6 += bf_lo(v0.w) * nT; a7 += bf_hi(v0.w) * nT;
        }
    }
    a0 += __shfl_xor(a0, 16); a1 += __shfl_xor(a1, 16);
    a2 += __shfl_xor(a2, 16); a3 += __shfl_xor(a3, 16);
    a4 += __shfl_xor(a4, 16); a5 += __shfl_xor(a5, 16);
    a6 += __shfl_xor(a6, 16); a7 += __shfl_xor(a7, 16);
    a0 += __shfl_xor(a0, 32); a1 += __shfl_xor(a1, 32);
    a2 += __shfl_xor(a2, 32); a3 += __shfl_xor(a3, 32);
    a4 += __shfl_xor(a4, 32); a5 += __shfl_xor(a5, 32);
    a6 += __shfl_xor(a6, 32); a7 += __shfl_xor(a7, 32);
    if (q == 0) {
        {   // implicit self-loop: dinv[wid]^2 * in[wid]
            uint4 sv = *(const uint4*)(in + (size_t)wid * HID + boff);
            float ss = dd * dd;
            a0 += bf_lo(sv.x) * ss; a1 += bf_hi(sv.x) * ss;
            a2 += bf_lo(sv.y) * ss; a3 += bf_hi(sv.y) * ss;
            a4 += bf_lo(sv.z) * ss; a5 += bf_hi(sv.z) * ss;
            a6 += bf_lo(sv.w) * ss; a7 += bf_hi(sv.w) * ss;
        }
        if (mode) {
            float4 b0 = *(const float4*)(bias + boff);
            float4 b1 = *(const float4*)(bias + boff + 4);
            a0 = fmaxf(a0 + b0.x, 0.f); a1 = fmaxf(a1 + b0.y, 0.f);
            a2 = fmaxf(a2 + b0.z, 0.f); a3 = fmaxf(a3 + b0.w, 0.f);
            a4 = fmaxf(a4 + b1.x, 0.f); a5 = fmaxf(a5 + b1.y, 0.f);
            a6 = fmaxf(a6 + b1.z, 0.f); a7 = fmaxf(a7 + b1.w, 0.f);
        }
        uint4 pk;
        pk.x = (uint)f2bf(a0) | ((uint)f2bf(a1) << 16);
        pk.y = (uint)f2bf(a2) | ((uint)f2bf(a3) << 16);
        pk.z = (uint)f2bf(a4) | ((uint)f2bf(a5) << 16);
        pk.w = (uint)f2bf(a6) | ((uint)f2bf(a7) << 16);
        *(uint4*)(out + (size_t)wid * HID + boff) = pk;
    }
}

// ---------------------------------------------------------------- GEMM2 (MFMA bf16): mu/ls[N,64] = g[N,128] @ W2T + bias
__global__ __launch_bounds__(256) void gemm2_mfma(const ushort* __restrict__ G,
                                                  const ushort* __restrict__ W2T,
                                                  const float* __restrict__ bmu,
                                                  const float* __restrict__ bls,
                                                  float* __restrict__ mu,
                                                  float* __restrict__ ls, int N) {
    __shared__ ushort As[64 * 32];
    __shared__ ushort Bs[128 * 32];
    __shared__ float  Cs[64 * 128];
    const int tid  = threadIdx.x;
    const int wave = tid >> 6, lane = tid & 63;
    const int q = lane >> 4, ln = lane & 15;
    const int row0 = blockIdx.x * 64;
    floatx4 acc[8] = {};

    for (int k0 = 0; k0 < HID; k0 += 32) {
        {   // A: 64 rows x 32 k bf16, 256 int4 chunks, 1/thread
            int r = tid >> 2, kc = (tid & 3) * 8;
            int4 v = make_int4(0, 0, 0, 0);
            if (row0 + r < N) v = *(const int4*)(G + (size_t)(row0 + r) * HID + k0 + kc);
            *(int4*)(As + r * 32 + kc) = v;
        }
        #pragma unroll
        for (int t = 0; t < 2; ++t) {            // B: 128 n x 32 k
            int c = t * 256 + tid;
            int n = c >> 2, kc = (c & 3) * 8;
            *(int4*)(Bs + n * 32 + kc) = *(const int4*)(W2T + (size_t)n * HID + k0 + kc);
        }
        __syncthreads();
        short8 a = *(const short8*)(As + (wave * 16 + ln) * 32 + q * 8);
        #pragma unroll
        for (int t = 0; t < 8; ++t) {
            short8 b = *(const short8*)(Bs + (t * 16 + ln) * 32 + q * 8);
            acc[t] = __builtin_amdgcn_mfma_f32_16x16x32_bf16(a, b, acc[t], 0, 0, 0);
        }
        __syncthreads();
    }
    #pragma unroll
    for (int t = 0; t < 8; ++t)
        #pragma unroll
        for (int r = 0; r < 4; ++r)
            Cs[(wave * 16 + q * 4 + r) * 128 + t * 16 + ln] = acc[t][r];
    __syncthreads();
    #pragma unroll
    for (int t = 0; t < 8; ++t) {
        int j = t * 256 + tid;                   // float4 id, 2048 total
        int r = j >> 5, c4 = (j & 31) * 4;
        if (row0 + r < N) {
            float4 v = *(const float4*)(Cs + r * 128 + c4);
            if (c4 < 64) {
                float4 b = *(const float4*)(bmu + c4);
                *(float4*)(mu + (size_t)(row0 + r) * LAT + c4) =
                    make_float4(v.x + b.x, v.y + b.y, v.z + b.z, v.w + b.w);
            } else {
                float4 b = *(const float4*)(bls + (c4 - 64));
                *(float4*)(ls + (size_t)(row0 + r) * LAT + (c4 - 64)) =
                    make_float4(v.x + b.x, v.y + b.y, v.z + b.z, v.w + b.w);
            }
        }
    }
}

// ---------------------------------------------------------------- launch
extern "C" void kernel_launch(void* const* d_in, const int* in_sizes, int n_in,
                              void* d_out, int out_size, void* d_ws, size_t ws_size,
                              hipStream_t stream) {
    const float* x    = (const float*)d_in[0];
    const int*   edge = (const int*)d_in[1];
    const float* W1   = (const float*)d_in[2];
    const float* b1   = (const float*)d_in[3];
    const float* Wmu  = (const float*)d_in[4];
    const float* bmu  = (const float*)d_in[5];
    const float* Wls  = (const float*)d_in[6];
    const float* bls  = (const float*)d_in[7];

    const int N    = in_sizes[0] / IN_DIM;
    const int E    = in_sizes[1] / 2;
    const int nbkt = (N + RANGE - 1) / RANGE;    // 500 at N=100000
    const int cap  = 4096;                       // bucket mean 3200, sigma ~57

    const int* src = edge;
    const int* dst = edge + E;

    // workspace layout (gb reuses t1b: consumed by agg1 before agg2 writes it)
    ushort* t1b  = (ushort*)d_ws;                        // [N,128] bf16  (also gb)
    ushort* hb   = t1b + (size_t)N * HID;                // [N,128] bf16
    int*    csr  = (int*)(hb + (size_t)N * HID);         // [N,64] padded src-only CSR
    int*    bkt  = (int*)(csr + (size_t)N * SLOTS);      // [MAXBKT,cap] int2 payload as 2x int
    float*  dinv = (float*)(bkt + (size_t)MAXBKT * cap * 2); // [N]
    int*    cur  = (int*)(dinv + N);                     // [N] in-degree (written densely by fill)
    int* bkt_cnt = cur + N;                              // [MAXBKT]
    ushort* W1T  = (ushort*)(bkt_cnt + MAXBKT);          // [128,256] bf16
    ushort* W2T  = W1T + IN_DIM * HID;                   // [128,128] bf16
    ushort* gb   = t1b;

    float* mu = (float*)d_out;                           // [N,64]
    float* ls = mu + (size_t)N * LAT;                    // [N,64]

    (void)hipMemsetAsync(bkt_cnt, 0, (size_t)MAXBKT * sizeof(int), stream);

    prep_weights<<<(IN_DIM * HID + 2 * HID * LAT) / 256, 256, 0, stream>>>(W1, Wmu, Wls, W1T, W2T);

    {   // fused scatter + gemm1 (independent; short scatter blocks -> true overlap)
        int sblocks  = (E + 2047) / 2048;        // 782
        int g1blocks = (N + 63) / 64;            // 1563
        scatter_gemm1_kernel<<<sblocks + g1blocks, 256, 0, stream>>>(
            src, dst, bkt, bkt_cnt, cap, nbkt, E, sblocks, x, W1T, t1b, N);
    }

    fill_bin_kernel<<<nbkt, 256, 0, stream>>>(bkt, bkt_cnt, cur, dinv, csr, cap, N);

    {   // layer-1 aggregation + bias + relu: t1b -> hb
        int blocks = (int)(((long long)N * 64 + 255) / 256);
        agg_kernel<<<blocks, 256, 0, stream>>>(t1b, hb, cur, csr, dinv, b1, N, 1);
    }
    {   // layer-2 aggregation: hb -> gb (= t1b, already consumed)
        int blocks = (int)(((long long)N * 64 + 255) / 256);
        agg_kernel<<<blocks, 256, 0, stream>>>(hb, gb, cur, csr, dinv, nullptr, N, 0);
    }

    gemm2_mfma<<<(N + 63) / 64, 256, 0, stream>>>(gb, W2T, bmu, bls, mu, ls, N);
}